// Round 3
// baseline (406.230 us; speedup 1.0000x reference)
//
#include <hip/hip_runtime.h>
#include <hip/hip_bf16.h>
#include <math.h>

// Invariant Point Attention (AlphaFold IPA), B=1, N=512, CS=384, CZ=128,
// H=12, C=16, PQ=4, PV=8. All f32.
// Round 2: round-1 structure (desk-audited), minor ILP tweaks. Still no HW
// feedback (3x GPUAcquisitionTimeout).
//  - fused per-i core kernel: logits -> softmax -> o/o_pt -> o_pair
//  - z read exactly twice from HBM (bias pass, o_pair pass), coalesced
//    float4 direct-global (no LDS staging of z)
//  - W_b multiplies come from scalar loads (lane-invariant address)
//  - register-blocked 64x64 GEMM (4x4/thread) for projections (4-target
//    fused) and for the K=2112 output projection (11-way K-split)

#define N_    512
#define CS_   384
#define CZ_   128
#define H_    12
#define INF_  100000.0f
#define EPS_  1e-8f

// ---------------------------------------------------------------------------
// Fused multi-target projection GEMM: C_t = s @ W_t + b_t for 4 targets.
// 64x64 tile / block, 256 threads, 4x4 micro-tile per thread, K-tile 16.
// ---------------------------------------------------------------------------
__global__ __launch_bounds__(256) void proj_gemm(
    const float* __restrict__ A,
    const float* __restrict__ W0, const float* __restrict__ b0, float* __restrict__ C0, int N0,
    const float* __restrict__ W1, const float* __restrict__ b1, float* __restrict__ C1, int N1,
    const float* __restrict__ W2, const float* __restrict__ b2, float* __restrict__ C2, int N2,
    const float* __restrict__ W3, const float* __restrict__ b3, float* __restrict__ C3, int N3)
{
    const float* W; const float* bias; float* C; int Nt;
    switch (blockIdx.z) {
        case 0:  W = W0; bias = b0; C = C0; Nt = N0; break;
        case 1:  W = W1; bias = b1; C = C1; Nt = N1; break;
        case 2:  W = W2; bias = b2; C = C2; Nt = N2; break;
        default: W = W3; bias = b3; C = C3; Nt = N3; break;
    }
    const int n0 = blockIdx.y * 64;
    if (n0 >= Nt) return;
    const int m0 = blockIdx.x * 64;

    __shared__ float As[16 * 68];   // [kk][m], padded
    __shared__ float Bs[16 * 68];   // [kk][n], padded
    const int t  = threadIdx.x;
    const int tm = t & 15;          // m-group
    const int tn = t >> 4;          // n-group

    float acc[4][4];
    #pragma unroll
    for (int r = 0; r < 4; ++r)
        #pragma unroll
        for (int c = 0; c < 4; ++c) acc[r][c] = 0.f;

    for (int k0 = 0; k0 < CS_; k0 += 16) {
        {   // stage A (transposed): thread loads s[m0+m][k0+kb..kb+3]
            int m = t >> 2, kb = (t & 3) * 4;
            float4 a4 = *(const float4*)(A + (size_t)(m0 + m) * CS_ + k0 + kb);
            As[(kb + 0) * 68 + m] = a4.x;
            As[(kb + 1) * 68 + m] = a4.y;
            As[(kb + 2) * 68 + m] = a4.z;
            As[(kb + 3) * 68 + m] = a4.w;
        }
        {   // stage B: thread loads W[k0+kk][n0+n..n+3] (guarded)
            int kk = t >> 4, n = (t & 15) * 4;
            int gn = n0 + n;
            const float* wr = W + (size_t)(k0 + kk) * Nt;
            float4 b4;
            b4.x = (gn + 0 < Nt) ? wr[gn + 0] : 0.f;
            b4.y = (gn + 1 < Nt) ? wr[gn + 1] : 0.f;
            b4.z = (gn + 2 < Nt) ? wr[gn + 2] : 0.f;
            b4.w = (gn + 3 < Nt) ? wr[gn + 3] : 0.f;
            *(float4*)(Bs + kk * 68 + n) = b4;
        }
        __syncthreads();
        #pragma unroll
        for (int kk = 0; kk < 16; ++kk) {
            float4 a4 = *(const float4*)(As + kk * 68 + tm * 4);
            float4 b4 = *(const float4*)(Bs + kk * 68 + tn * 4);
            float am[4] = {a4.x, a4.y, a4.z, a4.w};
            float bn[4] = {b4.x, b4.y, b4.z, b4.w};
            #pragma unroll
            for (int r = 0; r < 4; ++r)
                #pragma unroll
                for (int c = 0; c < 4; ++c)
                    acc[r][c] = fmaf(am[r], bn[c], acc[r][c]);
        }
        __syncthreads();
    }
    #pragma unroll
    for (int r = 0; r < 4; ++r) {
        int gm = m0 + tm * 4 + r;
        int gn = n0 + tn * 4;
        float* cr = C + (size_t)gm * Nt;
        #pragma unroll
        for (int c = 0; c < 4; ++c)
            if (gn + c < Nt) cr[gn + c] = acc[r][c] + bias[gn + c];
    }
}

// ---------------------------------------------------------------------------
// Output GEMM: P[kc] = cat[:, kc*192:(kc+1)*192] @ W_out[kc*192:...,:]
// M=512, N=384, K=2112 split 11 ways. Same micro-kernel, no edge guards.
// ---------------------------------------------------------------------------
__global__ __launch_bounds__(256) void gemm_ksplit(
    const float* __restrict__ A, const float* __restrict__ W,
    float* __restrict__ P)
{
    const int kc = blockIdx.z;
    const int m0 = blockIdx.x * 64;
    const int n0 = blockIdx.y * 64;

    __shared__ float As[16 * 68];
    __shared__ float Bs[16 * 68];
    const int t  = threadIdx.x;
    const int tm = t & 15;
    const int tn = t >> 4;

    float acc[4][4];
    #pragma unroll
    for (int r = 0; r < 4; ++r)
        #pragma unroll
        for (int c = 0; c < 4; ++c) acc[r][c] = 0.f;

    const int kbeg = kc * 192;
    for (int k0 = kbeg; k0 < kbeg + 192; k0 += 16) {
        {
            int m = t >> 2, kb = (t & 3) * 4;
            float4 a4 = *(const float4*)(A + (size_t)(m0 + m) * 2112 + k0 + kb);
            As[(kb + 0) * 68 + m] = a4.x;
            As[(kb + 1) * 68 + m] = a4.y;
            As[(kb + 2) * 68 + m] = a4.z;
            As[(kb + 3) * 68 + m] = a4.w;
        }
        {
            int kk = t >> 4, n = (t & 15) * 4;
            float4 b4 = *(const float4*)(W + (size_t)(k0 + kk) * 384 + n0 + n);
            *(float4*)(Bs + kk * 68 + n) = b4;
        }
        __syncthreads();
        #pragma unroll
        for (int kk = 0; kk < 16; ++kk) {
            float4 a4 = *(const float4*)(As + kk * 68 + tm * 4);
            float4 b4 = *(const float4*)(Bs + kk * 68 + tn * 4);
            float am[4] = {a4.x, a4.y, a4.z, a4.w};
            float bn[4] = {b4.x, b4.y, b4.z, b4.w};
            #pragma unroll
            for (int r = 0; r < 4; ++r)
                #pragma unroll
                for (int c = 0; c < 4; ++c)
                    acc[r][c] = fmaf(am[r], bn[c], acc[r][c]);
        }
        __syncthreads();
    }
    float* Pk = P + (size_t)kc * (512 * 384);
    #pragma unroll
    for (int r = 0; r < 4; ++r) {
        int gm = m0 + tm * 4 + r;
        *(float4*)(Pk + (size_t)gm * 384 + n0 + tn * 4) =
            make_float4(acc[r][0], acc[r][1], acc[r][2], acc[r][3]);
    }
}

__global__ __launch_bounds__(256) void reduce_out(
    const float* __restrict__ P, const float* __restrict__ bias,
    float* __restrict__ out)
{
    int idx = blockIdx.x * 256 + threadIdx.x;   // float4 index, 49152 total
    const float4* b4 = (const float4*)bias;
    float4 s = b4[idx % 96];
    const float4* P4 = (const float4*)P;
    #pragma unroll
    for (int g = 0; g < 11; ++g) {
        float4 v = P4[(size_t)g * 49152 + idx];
        s.x += v.x; s.y += v.y; s.z += v.z; s.w += v.w;
    }
    ((float4*)out)[idx] = s;
}

// ---------------------------------------------------------------------------
// Points + transposes. Block per n (192 threads).
//   qp[n][48pt][3], kp[n][48pt][3]  (pt = h*4+p)
//   vpT[h*24 + p*3 + d][512], vT[h*16+c][512]
// ---------------------------------------------------------------------------
__global__ __launch_bounds__(192) void prep_points(
    const float* __restrict__ lqp, const float* __restrict__ lkvp,
    const float* __restrict__ rot, const float* __restrict__ trans,
    const float* __restrict__ kvb,
    float* __restrict__ qp, float* __restrict__ kp,
    float* __restrict__ vT, float* __restrict__ vpT)
{
    const int n = blockIdx.x;
    const int t = threadIdx.x;
    const float* R = rot   + n * 9;
    const float* T = trans + n * 3;

    if (t < 48) {
        float p0 = lqp[n * 144 + t];
        float p1 = lqp[n * 144 + 48 + t];
        float p2 = lqp[n * 144 + 96 + t];
        float* d = qp + n * 144 + t * 3;
        d[0] = R[0]*p0 + R[1]*p1 + R[2]*p2 + T[0];
        d[1] = R[3]*p0 + R[4]*p1 + R[5]*p2 + T[1];
        d[2] = R[6]*p0 + R[7]*p1 + R[8]*p2 + T[2];
    } else {
        int jj = t - 48;    // 0..143
        float p0 = lkvp[n * 432 + jj];
        float p1 = lkvp[n * 432 + 144 + jj];
        float p2 = lkvp[n * 432 + 288 + jj];
        float g0 = R[0]*p0 + R[1]*p1 + R[2]*p2 + T[0];
        float g1 = R[3]*p0 + R[4]*p1 + R[5]*p2 + T[1];
        float g2 = R[6]*p0 + R[7]*p1 + R[8]*p2 + T[2];
        int h = jj / 12, idx = jj % 12;
        if (idx < 4) {
            float* d = kp + n * 144 + (h * 4 + idx) * 3;
            d[0] = g0; d[1] = g1; d[2] = g2;
        } else {
            int r = (idx - 4) * 3;
            vpT[(size_t)(h * 24 + r + 0) * N_ + n] = g0;
            vpT[(size_t)(h * 24 + r + 1) * N_ + n] = g1;
            vpT[(size_t)(h * 24 + r + 2) * N_ + n] = g2;
        }
    }
    // v transpose: vT[h*16+c][n] = kvb[n][h*32+16+c]
    vT[(size_t)t * N_ + n] = kvb[(size_t)n * 384 + (t >> 4) * 32 + 16 + (t & 15)];
}

// ---------------------------------------------------------------------------
// Fused IPA core, one block per residue i (512 blocks x 256 threads).
// Phase 1: logits (z pass 1, W_b scalar-loaded)  Phase 2: softmax (in LDS)
// Phase 3: o = a.v, o_pt = a.v_pts + rot^T/norm  Phase 4: o_pair (z pass 2)
// ---------------------------------------------------------------------------
__global__ __launch_bounds__(256) void ipa_core(
    const float* __restrict__ z,   const float* __restrict__ q,
    const float* __restrict__ kvb, const float* __restrict__ qp,
    const float* __restrict__ kp,  const float* __restrict__ vT,
    const float* __restrict__ vpT, const float* __restrict__ Wb,
    const float* __restrict__ bb,  const float* __restrict__ hwraw,
    const float* __restrict__ mask,const float* __restrict__ rot,
    const float* __restrict__ trans, float* __restrict__ cat)
{
    __shared__ float a_s[12 * 516];     // logits/probs, stride 516 (f4-friendly)
    __shared__ float pb[8 * 6 * 132];   // o_pair partials [jg][hh][132]; also o_pt staging

    const int i = blockIdx.x;
    const int t = threadIdx.x;

    const float sc_qk = 0.14433756729740643f;   // sqrt(1/48)
    const float sc_b  = 0.5773502691896258f;    // sqrt(1/3)
    const float sc_hw = 0.13608276348795434f;   // sqrt(1/54)

    const float mi = mask[i];
    float hw12[12], bb12[12];
    #pragma unroll
    for (int h = 0; h < 12; ++h) {
        float x = hwraw[h];
        hw12[h] = ((x > 20.f) ? x : log1pf(__expf(x))) * sc_hw;
        bb12[h] = bb[h];
    }

    const float4* qv  = (const float4*)(q  + (size_t)i * 192);  // uniform
    const float4* qpv = (const float4*)(qp + (size_t)i * 144);  // uniform

    // ---------------- Phase 1: logits ----------------
    for (int jj = 0; jj < 2; ++jj) {
        const int j = t + jj * 256;
        float bias[12];
        #pragma unroll
        for (int h = 0; h < 12; ++h) bias[h] = bb12[h];

        // bias = z[i,j,:] . W_b  — z coalesced float4 (thread owns row j),
        // W_b address lane-invariant -> scalar loads, zero LDS traffic.
        const float4* zr = (const float4*)z + ((size_t)i * N_ + j) * 32;
        #pragma unroll 16
        for (int c4 = 0; c4 < 32; ++c4) {
            float4 z4 = zr[c4];
            float zc[4] = {z4.x, z4.y, z4.z, z4.w};
            #pragma unroll
            for (int cc = 0; cc < 4; ++cc) {
                #pragma unroll
                for (int h = 0; h < 12; ++h)
                    bias[h] = fmaf(zc[cc], Wb[(c4 * 4 + cc) * 12 + h], bias[h]);
            }
        }

        const float mt = INF_ * (mi * mask[j] - 1.f);
        const float4* kr  = (const float4*)(kvb + (size_t)j * 384);
        const float4* kpr = (const float4*)(kp  + (size_t)j * 144);
        #pragma unroll
        for (int h = 0; h < 12; ++h) {
            float qk = 0.f;
            #pragma unroll
            for (int c4 = 0; c4 < 4; ++c4) {
                float4 qh = qv[h * 4 + c4];
                float4 kh = kr[h * 8 + c4];
                qk = fmaf(qh.x, kh.x, qk);
                qk = fmaf(qh.y, kh.y, qk);
                qk = fmaf(qh.z, kh.z, qk);
                qk = fmaf(qh.w, kh.w, qk);
            }
            float pt = 0.f;
            #pragma unroll
            for (int r = 0; r < 3; ++r) {
                float4 qh = qpv[h * 3 + r];
                float4 kh = kpr[h * 3 + r];
                float d0 = qh.x - kh.x, d1 = qh.y - kh.y;
                float d2 = qh.z - kh.z, d3 = qh.w - kh.w;
                pt = fmaf(d0, d0, pt); pt = fmaf(d1, d1, pt);
                pt = fmaf(d2, d2, pt); pt = fmaf(d3, d3, pt);
            }
            a_s[h * 516 + j] = fmaf(qk, sc_qk,
                               fmaf(bias[h], sc_b,
                               fmaf(-0.5f * hw12[h], pt, mt)));
        }
    }
    __syncthreads();

    // ---------------- Phase 2: softmax (rows in LDS) ----------------
    {
        const int w = t >> 6, lane = t & 63;
        #pragma unroll
        for (int hh = 0; hh < 3; ++hh) {
            const int h = w + hh * 4;
            float* row = a_s + h * 516;
            float4 v0 = *(float4*)(row + lane * 8);
            float4 v1 = *(float4*)(row + lane * 8 + 4);
            float m = fmaxf(fmaxf(fmaxf(v0.x, v0.y), fmaxf(v0.z, v0.w)),
                            fmaxf(fmaxf(v1.x, v1.y), fmaxf(v1.z, v1.w)));
            #pragma unroll
            for (int off = 32; off > 0; off >>= 1)
                m = fmaxf(m, __shfl_xor(m, off));
            v0.x = __expf(v0.x - m); v0.y = __expf(v0.y - m);
            v0.z = __expf(v0.z - m); v0.w = __expf(v0.w - m);
            v1.x = __expf(v1.x - m); v1.y = __expf(v1.y - m);
            v1.z = __expf(v1.z - m); v1.w = __expf(v1.w - m);
            float s = v0.x + v0.y + v0.z + v0.w + v1.x + v1.y + v1.z + v1.w;
            #pragma unroll
            for (int off = 32; off > 0; off >>= 1)
                s += __shfl_xor(s, off);
            float inv = 1.f / s;
            v0.x *= inv; v0.y *= inv; v0.z *= inv; v0.w *= inv;
            v1.x *= inv; v1.y *= inv; v1.z *= inv; v1.w *= inv;
            *(float4*)(row + lane * 8)     = v0;
            *(float4*)(row + lane * 8 + 4) = v1;
        }
    }
    __syncthreads();

    // ---------------- Phase 3: o = a.v, o_pt = a.v_pts ----------------
    float* opt_s = pb;   // first 288 floats reused for o_pt staging
    #pragma unroll
    for (int rnd = 0; rnd < 2; ++rnd) {
        const int oi = t + rnd * 256;
        if (oi < 480) {
            int h;
            const float* src;
            if (oi < 192) { h = oi >> 4;        src = vT  + (size_t)oi * N_; }
            else          { int pi = oi - 192; h = pi / 24; src = vpT + (size_t)pi * N_; }
            const float4* s4  = (const float4*)src;
            const float4* a4p = (const float4*)(a_s + h * 516);
            float acc = 0.f;
            #pragma unroll 4
            for (int j4 = 0; j4 < 128; ++j4) {
                float4 a4 = a4p[j4];
                float4 v4 = s4[j4];
                acc = fmaf(a4.x, v4.x, acc);
                acc = fmaf(a4.y, v4.y, acc);
                acc = fmaf(a4.z, v4.z, acc);
                acc = fmaf(a4.w, v4.w, acc);
            }
            if (oi < 192) cat[(size_t)i * 2112 + oi] = acc;
            else          opt_s[oi - 192] = acc;
        }
    }
    __syncthreads();

    if (t < 96) {   // finish points: rot^T (g - trans), norm
        const float* R = rot   + i * 9;
        const float* T = trans + i * 3;
        float g0 = opt_s[t * 3 + 0] - T[0];
        float g1 = opt_s[t * 3 + 1] - T[1];
        float g2 = opt_s[t * 3 + 2] - T[2];
        float x  = R[0]*g0 + R[3]*g1 + R[6]*g2;
        float y  = R[1]*g0 + R[4]*g1 + R[7]*g2;
        float zz = R[2]*g0 + R[5]*g1 + R[8]*g2;
        float nrm = sqrtf(x*x + y*y + zz*zz + EPS_);
        float* cr = cat + (size_t)i * 2112;
        cr[192 + t] = x;
        cr[288 + t] = y;
        cr[384 + t] = zz;
        cr[480 + t] = nrm;
    }
    __syncthreads();

    // ---------------- Phase 4: o_pair = a . z  (z pass 2) ----------------
    {
        const int c4 = t & 31;          // float4 column group
        const int jg = t >> 5;          // 0..7, 64 j each
        float4 acc[12];
        #pragma unroll
        for (int h = 0; h < 12; ++h) acc[h] = make_float4(0.f, 0.f, 0.f, 0.f);

        const float4* zr = (const float4*)z + (size_t)i * (N_ * 32) + c4;
        for (int j4b = 0; j4b < 16; ++j4b) {
            const int jb = jg * 64 + j4b * 4;
            float4 zv[4];
            #pragma unroll
            for (int u = 0; u < 4; ++u) zv[u] = zr[(size_t)(jb + u) * 32];
            #pragma unroll
            for (int h = 0; h < 12; ++h) {
                float4 a4 = *(const float4*)(a_s + h * 516 + jb);
                acc[h].x = fmaf(a4.x, zv[0].x, acc[h].x);
                acc[h].y = fmaf(a4.x, zv[0].y, acc[h].y);
                acc[h].z = fmaf(a4.x, zv[0].z, acc[h].z);
                acc[h].w = fmaf(a4.x, zv[0].w, acc[h].w);
                acc[h].x = fmaf(a4.y, zv[1].x, acc[h].x);
                acc[h].y = fmaf(a4.y, zv[1].y, acc[h].y);
                acc[h].z = fmaf(a4.y, zv[1].z, acc[h].z);
                acc[h].w = fmaf(a4.y, zv[1].w, acc[h].w);
                acc[h].x = fmaf(a4.z, zv[2].x, acc[h].x);
                acc[h].y = fmaf(a4.z, zv[2].y, acc[h].y);
                acc[h].z = fmaf(a4.z, zv[2].z, acc[h].z);
                acc[h].w = fmaf(a4.z, zv[2].w, acc[h].w);
                acc[h].x = fmaf(a4.w, zv[3].x, acc[h].x);
                acc[h].y = fmaf(a4.w, zv[3].y, acc[h].y);
                acc[h].z = fmaf(a4.w, zv[3].z, acc[h].z);
                acc[h].w = fmaf(a4.w, zv[3].w, acc[h].w);
            }
        }

        // reduce across jg in two h-halves (LDS budget)
        #pragma unroll
        for (int half = 0; half < 2; ++half) {
            __syncthreads();
            #pragma unroll
            for (int hh = 0; hh < 6; ++hh)
                *(float4*)(pb + (size_t)(jg * 6 + hh) * 132 + c4 * 4) = acc[half * 6 + hh];
            __syncthreads();
            #pragma unroll
            for (int k = 0; k < 3; ++k) {
                const int idx = t + k * 256;          // 0..767
                const int hh = idx >> 7, c = idx & 127;
                float s = 0.f;
                #pragma unroll
                for (int g = 0; g < 8; ++g)
                    s += pb[(size_t)(g * 6 + hh) * 132 + c];
                cat[(size_t)i * 2112 + 576 + half * 768 + idx] = s;
            }
        }
    }
}

// ---------------------------------------------------------------------------
extern "C" void kernel_launch(void* const* d_in, const int* in_sizes, int n_in,
                              void* d_out, int out_size, void* d_ws, size_t ws_size,
                              hipStream_t stream)
{
    const float* s     = (const float*)d_in[0];
    const float* z     = (const float*)d_in[1];
    const float* rot   = (const float*)d_in[2];
    const float* trans = (const float*)d_in[3];
    const float* mask  = (const float*)d_in[4];
    const float* W_q   = (const float*)d_in[5];
    const float* b_q   = (const float*)d_in[6];
    const float* W_kv  = (const float*)d_in[7];
    const float* b_kv  = (const float*)d_in[8];
    const float* W_qp  = (const float*)d_in[9];
    const float* b_qp  = (const float*)d_in[10];
    const float* W_kvp = (const float*)d_in[11];
    const float* b_kvp = (const float*)d_in[12];
    const float* W_b   = (const float*)d_in[13];
    const float* b_b   = (const float*)d_in[14];
    const float* hw    = (const float*)d_in[15];
    const float* W_out = (const float*)d_in[16];
    const float* b_out = (const float*)d_in[17];
    float* out = (float*)d_out;
    float* ws  = (float*)d_ws;

    // workspace layout (floats), total ~16.9 MB
    float* q     = ws;                     // 512*192
    float* kvb   = q     + 512 * 192;      // 512*384
    float* lqp   = kvb   + 512 * 384;      // 512*144
    float* lkvp  = lqp   + 512 * 144;      // 512*432
    float* qp    = lkvp  + 512 * 432;      // 512*144
    float* kp    = qp    + 512 * 144;      // 512*144
    float* vT    = kp    + 512 * 144;      // 192*512
    float* vpT   = vT    + 192 * 512;      // 288*512
    float* cat   = vpT   + 288 * 512;      // 512*2112
    float* gpart = cat   + 512 * 2112;     // 11*512*384

    // 1) fused input projections
    proj_gemm<<<dim3(8, 7, 4), 256, 0, stream>>>(
        s,
        W_q,   b_q,   q,    192,
        W_kv,  b_kv,  kvb,  384,
        W_qp,  b_qp,  lqp,  144,
        W_kvp, b_kvp, lkvp, 432);
    // 2) points + v transposes
    prep_points<<<512, 192, 0, stream>>>(lqp, lkvp, rot, trans, kvb, qp, kp, vT, vpT);
    // 3) fused IPA core (z read exactly twice)
    ipa_core<<<512, 256, 0, stream>>>(z, q, kvb, qp, kp, vT, vpT,
                                      W_b, b_b, hw, mask, rot, trans, cat);
    // 4) output projection (K-split) + reduce
    gemm_ksplit<<<dim3(8, 6, 11), 256, 0, stream>>>(cat, W_out, gpart);
    reduce_out<<<192, 256, 0, stream>>>(gpart, b_out, out);
}

// Round 4
// 387.458 us; speedup vs baseline: 1.0484x; 1.0484x over previous
//
#include <hip/hip_runtime.h>
#include <hip/hip_bf16.h>
#include <math.h>

// Invariant Point Attention (AlphaFold IPA), B=1, N=512, CS=384, CZ=128,
// H=12, C=16, PQ=4, PV=8. All f32.
// Round 3: fix address divergence found in round-2 profile (ipa_core 174us,
// 11% HBM, latency-bound):
//  - phase 1: z staged via coalesced 64-row LDS tiles; wave-per-3-heads with
//    readfirstlane -> W_b/q/q_pts all scalar loads
//  - phase 3: vcat[j][512] combined row layout, coalesced float2 streams
//  - phase 4 unchanged (already coalesced, L3-fed second z pass)

#define N_    512
#define CS_   384
#define CZ_   128
#define H_    12
#define INF_  100000.0f
#define EPS_  1e-8f

// ---------------------------------------------------------------------------
// Fused multi-target projection GEMM: C_t = s @ W_t + b_t for 4 targets.
// ---------------------------------------------------------------------------
__global__ __launch_bounds__(256) void proj_gemm(
    const float* __restrict__ A,
    const float* __restrict__ W0, const float* __restrict__ b0, float* __restrict__ C0, int N0,
    const float* __restrict__ W1, const float* __restrict__ b1, float* __restrict__ C1, int N1,
    const float* __restrict__ W2, const float* __restrict__ b2, float* __restrict__ C2, int N2,
    const float* __restrict__ W3, const float* __restrict__ b3, float* __restrict__ C3, int N3)
{
    const float* W; const float* bias; float* C; int Nt;
    switch (blockIdx.z) {
        case 0:  W = W0; bias = b0; C = C0; Nt = N0; break;
        case 1:  W = W1; bias = b1; C = C1; Nt = N1; break;
        case 2:  W = W2; bias = b2; C = C2; Nt = N2; break;
        default: W = W3; bias = b3; C = C3; Nt = N3; break;
    }
    const int n0 = blockIdx.y * 64;
    if (n0 >= Nt) return;
    const int m0 = blockIdx.x * 64;

    __shared__ float As[16 * 68];   // [kk][m], padded
    __shared__ float Bs[16 * 68];   // [kk][n], padded
    const int t  = threadIdx.x;
    const int tm = t & 15;
    const int tn = t >> 4;

    float acc[4][4];
    #pragma unroll
    for (int r = 0; r < 4; ++r)
        #pragma unroll
        for (int c = 0; c < 4; ++c) acc[r][c] = 0.f;

    for (int k0 = 0; k0 < CS_; k0 += 16) {
        {
            int m = t >> 2, kb = (t & 3) * 4;
            float4 a4 = *(const float4*)(A + (size_t)(m0 + m) * CS_ + k0 + kb);
            As[(kb + 0) * 68 + m] = a4.x;
            As[(kb + 1) * 68 + m] = a4.y;
            As[(kb + 2) * 68 + m] = a4.z;
            As[(kb + 3) * 68 + m] = a4.w;
        }
        {
            int kk = t >> 4, n = (t & 15) * 4;
            int gn = n0 + n;
            const float* wr = W + (size_t)(k0 + kk) * Nt;
            float4 b4;
            b4.x = (gn + 0 < Nt) ? wr[gn + 0] : 0.f;
            b4.y = (gn + 1 < Nt) ? wr[gn + 1] : 0.f;
            b4.z = (gn + 2 < Nt) ? wr[gn + 2] : 0.f;
            b4.w = (gn + 3 < Nt) ? wr[gn + 3] : 0.f;
            *(float4*)(Bs + kk * 68 + n) = b4;
        }
        __syncthreads();
        #pragma unroll
        for (int kk = 0; kk < 16; ++kk) {
            float4 a4 = *(const float4*)(As + kk * 68 + tm * 4);
            float4 b4 = *(const float4*)(Bs + kk * 68 + tn * 4);
            float am[4] = {a4.x, a4.y, a4.z, a4.w};
            float bn[4] = {b4.x, b4.y, b4.z, b4.w};
            #pragma unroll
            for (int r = 0; r < 4; ++r)
                #pragma unroll
                for (int c = 0; c < 4; ++c)
                    acc[r][c] = fmaf(am[r], bn[c], acc[r][c]);
        }
        __syncthreads();
    }
    #pragma unroll
    for (int r = 0; r < 4; ++r) {
        int gm = m0 + tm * 4 + r;
        int gn = n0 + tn * 4;
        float* cr = C + (size_t)gm * Nt;
        #pragma unroll
        for (int c = 0; c < 4; ++c)
            if (gn + c < Nt) cr[gn + c] = acc[r][c] + bias[gn + c];
    }
}

// ---------------------------------------------------------------------------
// Output GEMM: K=2112 split 11 ways into gpart[kc][512][384].
// ---------------------------------------------------------------------------
__global__ __launch_bounds__(256) void gemm_ksplit(
    const float* __restrict__ A, const float* __restrict__ W,
    float* __restrict__ P)
{
    const int kc = blockIdx.z;
    const int m0 = blockIdx.x * 64;
    const int n0 = blockIdx.y * 64;

    __shared__ float As[16 * 68];
    __shared__ float Bs[16 * 68];
    const int t  = threadIdx.x;
    const int tm = t & 15;
    const int tn = t >> 4;

    float acc[4][4];
    #pragma unroll
    for (int r = 0; r < 4; ++r)
        #pragma unroll
        for (int c = 0; c < 4; ++c) acc[r][c] = 0.f;

    const int kbeg = kc * 192;
    for (int k0 = kbeg; k0 < kbeg + 192; k0 += 16) {
        {
            int m = t >> 2, kb = (t & 3) * 4;
            float4 a4 = *(const float4*)(A + (size_t)(m0 + m) * 2112 + k0 + kb);
            As[(kb + 0) * 68 + m] = a4.x;
            As[(kb + 1) * 68 + m] = a4.y;
            As[(kb + 2) * 68 + m] = a4.z;
            As[(kb + 3) * 68 + m] = a4.w;
        }
        {
            int kk = t >> 4, n = (t & 15) * 4;
            float4 b4 = *(const float4*)(W + (size_t)(k0 + kk) * 384 + n0 + n);
            *(float4*)(Bs + kk * 68 + n) = b4;
        }
        __syncthreads();
        #pragma unroll
        for (int kk = 0; kk < 16; ++kk) {
            float4 a4 = *(const float4*)(As + kk * 68 + tm * 4);
            float4 b4 = *(const float4*)(Bs + kk * 68 + tn * 4);
            float am[4] = {a4.x, a4.y, a4.z, a4.w};
            float bn[4] = {b4.x, b4.y, b4.z, b4.w};
            #pragma unroll
            for (int r = 0; r < 4; ++r)
                #pragma unroll
                for (int c = 0; c < 4; ++c)
                    acc[r][c] = fmaf(am[r], bn[c], acc[r][c]);
        }
        __syncthreads();
    }
    float* Pk = P + (size_t)kc * (512 * 384);
    #pragma unroll
    for (int r = 0; r < 4; ++r) {
        int gm = m0 + tm * 4 + r;
        *(float4*)(Pk + (size_t)gm * 384 + n0 + tn * 4) =
            make_float4(acc[r][0], acc[r][1], acc[r][2], acc[r][3]);
    }
}

__global__ __launch_bounds__(256) void reduce_out(
    const float* __restrict__ P, const float* __restrict__ bias,
    float* __restrict__ out)
{
    int idx = blockIdx.x * 256 + threadIdx.x;   // float4 index, 49152 total
    const float4* b4 = (const float4*)bias;
    float4 s = b4[idx % 96];
    const float4* P4 = (const float4*)P;
    #pragma unroll
    for (int g = 0; g < 11; ++g) {
        float4 v = P4[(size_t)g * 49152 + idx];
        s.x += v.x; s.y += v.y; s.z += v.z; s.w += v.w;
    }
    ((float4*)out)[idx] = s;
}

// ---------------------------------------------------------------------------
// Points + combined value row layout.
//   qp[n][48pt][3], kp[n][48pt][3]  (pt = h*4+p)
//   vcat[n][512]: cols 0..191 = v (h*16+c), 192..479 = v_pts (h*24+p*3+d)
// ---------------------------------------------------------------------------
__global__ __launch_bounds__(192) void prep_points(
    const float* __restrict__ lqp, const float* __restrict__ lkvp,
    const float* __restrict__ rot, const float* __restrict__ trans,
    const float* __restrict__ kvb,
    float* __restrict__ qp, float* __restrict__ kp,
    float* __restrict__ vcat)
{
    const int n = blockIdx.x;
    const int t = threadIdx.x;
    const float* R = rot   + n * 9;
    const float* T = trans + n * 3;

    if (t < 48) {
        float p0 = lqp[n * 144 + t];
        float p1 = lqp[n * 144 + 48 + t];
        float p2 = lqp[n * 144 + 96 + t];
        float* d = qp + n * 144 + t * 3;
        d[0] = R[0]*p0 + R[1]*p1 + R[2]*p2 + T[0];
        d[1] = R[3]*p0 + R[4]*p1 + R[5]*p2 + T[1];
        d[2] = R[6]*p0 + R[7]*p1 + R[8]*p2 + T[2];
    } else {
        int jj = t - 48;    // 0..143
        float p0 = lkvp[n * 432 + jj];
        float p1 = lkvp[n * 432 + 144 + jj];
        float p2 = lkvp[n * 432 + 288 + jj];
        float g0 = R[0]*p0 + R[1]*p1 + R[2]*p2 + T[0];
        float g1 = R[3]*p0 + R[4]*p1 + R[5]*p2 + T[1];
        float g2 = R[6]*p0 + R[7]*p1 + R[8]*p2 + T[2];
        int h = jj / 12, idx = jj % 12;
        if (idx < 4) {
            float* d = kp + n * 144 + (h * 4 + idx) * 3;
            d[0] = g0; d[1] = g1; d[2] = g2;
        } else {
            float* d = vcat + (size_t)n * 512 + 192 + h * 24 + (idx - 4) * 3;
            d[0] = g0; d[1] = g1; d[2] = g2;
        }
    }
    // v part: vcat[n][h*16+c] = kvb[n][h*32+16+c]
    vcat[(size_t)n * 512 + t] = kvb[(size_t)n * 384 + (t >> 4) * 32 + 16 + (t & 15)];
}

// ---------------------------------------------------------------------------
// Fused IPA core, one block per residue i (512 blocks x 256 threads).
// ---------------------------------------------------------------------------
__global__ __launch_bounds__(256) void ipa_core(
    const float* __restrict__ z,   const float* __restrict__ q,
    const float* __restrict__ kvb, const float* __restrict__ qp,
    const float* __restrict__ kp,  const float* __restrict__ vcat,
    const float* __restrict__ Wb,  const float* __restrict__ bb,
    const float* __restrict__ hwraw, const float* __restrict__ mask,
    const float* __restrict__ rot, const float* __restrict__ trans,
    float* __restrict__ cat)
{
    __shared__ float4 a_s4[1548];   // 12*516 floats (logits/probs)
    __shared__ float4 pb4[2112];    // 8448 floats: z-tile (ph1) / opt staging
                                    //   (ph3) / o_pair partials (ph4)
    float* a_s = (float*)a_s4;
    float* pb  = (float*)pb4;

    const int i    = blockIdx.x;
    const int t    = threadIdx.x;
    const int lane = t & 63;

    const float sc_qk = 0.14433756729740643f;   // sqrt(1/48)
    const float sc_b  = 0.5773502691896258f;    // sqrt(1/3)
    const float sc_hw = 0.13608276348795434f;   // sqrt(1/54)

    const float mi = mask[i];

    // wave-uniform head triple (forced into SGPR so Wb/q/qp loads scalarize)
    const int h0 = __builtin_amdgcn_readfirstlane((t >> 6) * 3);
    const float bbA = bb[h0],     bbB = bb[h0 + 1],     bbC = bb[h0 + 2];
    float xA = hwraw[h0], xB = hwraw[h0 + 1], xC = hwraw[h0 + 2];
    const float hwA = ((xA > 20.f) ? xA : log1pf(__expf(xA))) * sc_hw;
    const float hwB = ((xB > 20.f) ? xB : log1pf(__expf(xB))) * sc_hw;
    const float hwC = ((xC > 20.f) ? xC : log1pf(__expf(xC))) * sc_hw;

    const float4* qv  = (const float4*)(q  + (size_t)i * 192);  // uniform idx
    const float4* qpv = (const float4*)(qp + (size_t)i * 144);  // uniform idx

    // ---------------- Phase 1: logits (z pass 1, coalesced via LDS) -------
    float* ztile = pb;   // [64][132]
    for (int tile = 0; tile < 8; ++tile) {
        const int jb = tile * 64;
        // stage 64 rows x 128 ch, fully coalesced
        const float4* zsrc = (const float4*)z + ((size_t)i * N_ + jb) * 32;
        #pragma unroll
        for (int k2 = 0; k2 < 8; ++k2) {
            int idx = t + k2 * 256;            // 0..2047
            int rr = idx >> 5, c4 = idx & 31;
            *(float4*)(ztile + rr * 132 + c4 * 4) = zsrc[(size_t)rr * 32 + c4];
        }
        __syncthreads();

        // lane = row, wave = 3 heads
        const int j = jb + lane;
        float b0 = bbA, b1 = bbB, b2 = bbC;
        const float4* zrow = (const float4*)(ztile + lane * 132);
        #pragma unroll 8
        for (int c4 = 0; c4 < 32; ++c4) {
            float4 z4 = zrow[c4];
            float zc[4] = {z4.x, z4.y, z4.z, z4.w};
            #pragma unroll
            for (int cc = 0; cc < 4; ++cc) {
                const int c = c4 * 4 + cc;
                b0 = fmaf(zc[cc], Wb[c * 12 + h0    ], b0);
                b1 = fmaf(zc[cc], Wb[c * 12 + h0 + 1], b1);
                b2 = fmaf(zc[cc], Wb[c * 12 + h0 + 2], b2);
            }
        }

        const float mt = INF_ * (mi * mask[j] - 1.f);
        const float4* kr  = (const float4*)(kvb + (size_t)j * 384);
        const float4* kpr = (const float4*)(kp  + (size_t)j * 144);
        #pragma unroll
        for (int hh = 0; hh < 3; ++hh) {
            const int h = h0 + hh;
            float qk = 0.f;
            #pragma unroll
            for (int c4 = 0; c4 < 4; ++c4) {
                float4 qh = qv[h * 4 + c4];     // scalar (uniform)
                float4 kh = kr[h * 8 + c4];
                qk = fmaf(qh.x, kh.x, qk);
                qk = fmaf(qh.y, kh.y, qk);
                qk = fmaf(qh.z, kh.z, qk);
                qk = fmaf(qh.w, kh.w, qk);
            }
            float pt = 0.f;
            #pragma unroll
            for (int r = 0; r < 3; ++r) {
                float4 qh = qpv[h * 3 + r];     // scalar (uniform)
                float4 kh = kpr[h * 3 + r];
                float d0 = qh.x - kh.x, d1 = qh.y - kh.y;
                float d2 = qh.z - kh.z, d3 = qh.w - kh.w;
                pt = fmaf(d0, d0, pt); pt = fmaf(d1, d1, pt);
                pt = fmaf(d2, d2, pt); pt = fmaf(d3, d3, pt);
            }
            float bsum = (hh == 0) ? b0 : (hh == 1) ? b1 : b2;
            float hwv  = (hh == 0) ? hwA : (hh == 1) ? hwB : hwC;
            a_s[h * 516 + j] = fmaf(qk, sc_qk,
                               fmaf(bsum, sc_b,
                               fmaf(-0.5f * hwv, pt, mt)));
        }
        __syncthreads();
    }

    // ---------------- Phase 2: softmax (rows in LDS) ----------------
    {
        const int w = t >> 6;
        #pragma unroll
        for (int hh = 0; hh < 3; ++hh) {
            const int h = w + hh * 4;
            float* row = a_s + h * 516;
            float4 v0 = *(float4*)(row + lane * 8);
            float4 v1 = *(float4*)(row + lane * 8 + 4);
            float m = fmaxf(fmaxf(fmaxf(v0.x, v0.y), fmaxf(v0.z, v0.w)),
                            fmaxf(fmaxf(v1.x, v1.y), fmaxf(v1.z, v1.w)));
            #pragma unroll
            for (int off = 32; off > 0; off >>= 1)
                m = fmaxf(m, __shfl_xor(m, off));
            v0.x = __expf(v0.x - m); v0.y = __expf(v0.y - m);
            v0.z = __expf(v0.z - m); v0.w = __expf(v0.w - m);
            v1.x = __expf(v1.x - m); v1.y = __expf(v1.y - m);
            v1.z = __expf(v1.z - m); v1.w = __expf(v1.w - m);
            float s = v0.x + v0.y + v0.z + v0.w + v1.x + v1.y + v1.z + v1.w;
            #pragma unroll
            for (int off = 32; off > 0; off >>= 1)
                s += __shfl_xor(s, off);
            float inv = 1.f / s;
            v0.x *= inv; v0.y *= inv; v0.z *= inv; v0.w *= inv;
            v1.x *= inv; v1.y *= inv; v1.z *= inv; v1.w *= inv;
            *(float4*)(row + lane * 8)     = v0;
            *(float4*)(row + lane * 8 + 4) = v1;
        }
    }
    __syncthreads();

    // ---------------- Phase 3: o = a.v, o_pt = a.v_pts (coalesced) --------
    float* opt_s = pb;   // 288 floats staging
    if (t < 240) {
        const int o0 = 2 * t;
        const int h  = (o0 < 192) ? (o0 >> 4) : ((o0 - 192) / 24);
        const float2* vrow = (const float2*)vcat + t;
        float accx = 0.f, accy = 0.f;
        #pragma unroll 4
        for (int j = 0; j < 512; ++j) {
            float2 v2 = vrow[(size_t)j * 256];
            float aj  = a_s[h * 516 + j];
            accx = fmaf(aj, v2.x, accx);
            accy = fmaf(aj, v2.y, accy);
        }
        if (o0 < 192) {
            cat[(size_t)i * 2112 + o0]     = accx;
            cat[(size_t)i * 2112 + o0 + 1] = accy;
        } else {
            opt_s[o0 - 192] = accx;
            opt_s[o0 - 191] = accy;
        }
    }
    __syncthreads();

    if (t < 96) {   // finish points: rot^T (g - trans), norm
        const float* R = rot   + i * 9;
        const float* T = trans + i * 3;
        float g0 = opt_s[t * 3 + 0] - T[0];
        float g1 = opt_s[t * 3 + 1] - T[1];
        float g2 = opt_s[t * 3 + 2] - T[2];
        float x  = R[0]*g0 + R[3]*g1 + R[6]*g2;
        float y  = R[1]*g0 + R[4]*g1 + R[7]*g2;
        float zz = R[2]*g0 + R[5]*g1 + R[8]*g2;
        float nrm = sqrtf(x*x + y*y + zz*zz + EPS_);
        float* cr = cat + (size_t)i * 2112;
        cr[192 + t] = x;
        cr[288 + t] = y;
        cr[384 + t] = zz;
        cr[480 + t] = nrm;
    }
    __syncthreads();

    // ---------------- Phase 4: o_pair = a . z  (z pass 2, L3-fed) ---------
    {
        const int c4 = t & 31;          // float4 column group
        const int jg = t >> 5;          // 0..7, 64 j each
        float4 acc[12];
        #pragma unroll
        for (int h = 0; h < 12; ++h) acc[h] = make_float4(0.f, 0.f, 0.f, 0.f);

        const float4* zr = (const float4*)z + (size_t)i * (N_ * 32) + c4;
        for (int j4b = 0; j4b < 16; ++j4b) {
            const int jb = jg * 64 + j4b * 4;
            float4 zv[4];
            #pragma unroll
            for (int u = 0; u < 4; ++u) zv[u] = zr[(size_t)(jb + u) * 32];
            #pragma unroll
            for (int h = 0; h < 12; ++h) {
                float4 a4 = *(const float4*)(a_s + h * 516 + jb);
                acc[h].x = fmaf(a4.x, zv[0].x, acc[h].x);
                acc[h].y = fmaf(a4.x, zv[0].y, acc[h].y);
                acc[h].z = fmaf(a4.x, zv[0].z, acc[h].z);
                acc[h].w = fmaf(a4.x, zv[0].w, acc[h].w);
                acc[h].x = fmaf(a4.y, zv[1].x, acc[h].x);
                acc[h].y = fmaf(a4.y, zv[1].y, acc[h].y);
                acc[h].z = fmaf(a4.y, zv[1].z, acc[h].z);
                acc[h].w = fmaf(a4.y, zv[1].w, acc[h].w);
                acc[h].x = fmaf(a4.z, zv[2].x, acc[h].x);
                acc[h].y = fmaf(a4.z, zv[2].y, acc[h].y);
                acc[h].z = fmaf(a4.z, zv[2].z, acc[h].z);
                acc[h].w = fmaf(a4.z, zv[2].w, acc[h].w);
                acc[h].x = fmaf(a4.w, zv[3].x, acc[h].x);
                acc[h].y = fmaf(a4.w, zv[3].y, acc[h].y);
                acc[h].z = fmaf(a4.w, zv[3].z, acc[h].z);
                acc[h].w = fmaf(a4.w, zv[3].w, acc[h].w);
            }
        }

        // reduce across jg in two h-halves
        #pragma unroll
        for (int half = 0; half < 2; ++half) {
            __syncthreads();
            #pragma unroll
            for (int hh = 0; hh < 6; ++hh)
                *(float4*)(pb + (size_t)(jg * 6 + hh) * 132 + c4 * 4) = acc[half * 6 + hh];
            __syncthreads();
            #pragma unroll
            for (int k = 0; k < 3; ++k) {
                const int idx = t + k * 256;          // 0..767
                const int hh = idx >> 7, c = idx & 127;
                float s = 0.f;
                #pragma unroll
                for (int g = 0; g < 8; ++g)
                    s += pb[(size_t)(g * 6 + hh) * 132 + c];
                cat[(size_t)i * 2112 + 576 + half * 768 + idx] = s;
            }
        }
    }
}

// ---------------------------------------------------------------------------
extern "C" void kernel_launch(void* const* d_in, const int* in_sizes, int n_in,
                              void* d_out, int out_size, void* d_ws, size_t ws_size,
                              hipStream_t stream)
{
    const float* s     = (const float*)d_in[0];
    const float* z     = (const float*)d_in[1];
    const float* rot   = (const float*)d_in[2];
    const float* trans = (const float*)d_in[3];
    const float* mask  = (const float*)d_in[4];
    const float* W_q   = (const float*)d_in[5];
    const float* b_q   = (const float*)d_in[6];
    const float* W_kv  = (const float*)d_in[7];
    const float* b_kv  = (const float*)d_in[8];
    const float* W_qp  = (const float*)d_in[9];
    const float* b_qp  = (const float*)d_in[10];
    const float* W_kvp = (const float*)d_in[11];
    const float* b_kvp = (const float*)d_in[12];
    const float* W_b   = (const float*)d_in[13];
    const float* b_b   = (const float*)d_in[14];
    const float* hw    = (const float*)d_in[15];
    const float* W_out = (const float*)d_in[16];
    const float* b_out = (const float*)d_in[17];
    float* out = (float*)d_out;
    float* ws  = (float*)d_ws;

    // workspace layout (floats), ~13 MB total.
    // gpart (written after ipa_core) overlaps the early buffers (dead by then).
    float* gpart = ws;                       // 11*512*384 = 2162688
    float* cat   = ws + 2162688;             // 512*2112   = 1081344
    float* q     = ws;                       // 98304   (overlaps gpart - OK)
    float* kvb   = q    + 98304;             // 196608
    float* lqp   = kvb  + 196608;            // 73728
    float* lkvp  = lqp  + 73728;             // 221184
    float* qp    = lkvp + 221184;            // 73728
    float* kp    = qp   + 73728;             // 73728
    float* vcat  = kp   + 73728;             // 262144 (ends at 999424 < 2162688)

    // 1) fused input projections
    proj_gemm<<<dim3(8, 7, 4), 256, 0, stream>>>(
        s,
        W_q,   b_q,   q,    192,
        W_kv,  b_kv,  kvb,  384,
        W_qp,  b_qp,  lqp,  144,
        W_kvp, b_kvp, lkvp, 432);
    // 2) points + vcat
    prep_points<<<512, 192, 0, stream>>>(lqp, lkvp, rot, trans, kvb, qp, kp, vcat);
    // 3) fused IPA core (z read exactly twice)
    ipa_core<<<512, 256, 0, stream>>>(z, q, kvb, qp, kp, vcat,
                                      W_b, b_b, hw, mask, rot, trans, cat);
    // 4) output projection (K-split) + reduce
    gemm_ksplit<<<dim3(8, 6, 11), 256, 0, stream>>>(cat, W_out, gpart);
    reduce_out<<<192, 256, 0, stream>>>(gpart, b_out, out);
}

// Round 5
// 374.227 us; speedup vs baseline: 1.0855x; 1.0354x over previous
//
#include <hip/hip_runtime.h>
#include <hip/hip_bf16.h>
#include <math.h>

// Invariant Point Attention (AlphaFold IPA), B=1, N=512, CS=384, CZ=128,
// H=12, C=16, PQ=4, PV=8. All f32.
// Round 4: split the monolithic per-i core (155us, 12% HBM, 25% occ,
// latency-bound) into GEMM-shaped + stream-shaped kernels:
//   qkpt_gemm : qk + point-dist + mask as 64x64xK28 GEMM per head -> att
//   logits_k  : z pass 1 (LDS-staged), bias GEMV, in-place add -> att
//   smax_av   : softmax + o + o_pt + point finish
//   opair_k   : z pass 2 (L3-fed), o_pair
// pt trick: |qp-kp|^2 = |qp|^2 + |kp|^2 - 2 qp.kp  (GEMM-able)

#define N_    512
#define CS_   384
#define INF_  100000.0f
#define EPS_  1e-8f

#define SC_QK 0.14433756729740643f   // sqrt(1/48)
#define SC_B  0.5773502691896258f    // sqrt(1/3)
#define SC_HW 0.13608276348795434f   // sqrt(1/54)

__device__ __forceinline__ float softplus_(float x) {
    return (x > 20.f) ? x : log1pf(__expf(x));
}

// ---------------------------------------------------------------------------
// Fused multi-target projection GEMM: C_t = s @ W_t + b_t for 4 targets.
// ---------------------------------------------------------------------------
__global__ __launch_bounds__(256) void proj_gemm(
    const float* __restrict__ A,
    const float* __restrict__ W0, const float* __restrict__ b0, float* __restrict__ C0, int N0,
    const float* __restrict__ W1, const float* __restrict__ b1, float* __restrict__ C1, int N1,
    const float* __restrict__ W2, const float* __restrict__ b2, float* __restrict__ C2, int N2,
    const float* __restrict__ W3, const float* __restrict__ b3, float* __restrict__ C3, int N3)
{
    const float* W; const float* bias; float* C; int Nt;
    switch (blockIdx.z) {
        case 0:  W = W0; bias = b0; C = C0; Nt = N0; break;
        case 1:  W = W1; bias = b1; C = C1; Nt = N1; break;
        case 2:  W = W2; bias = b2; C = C2; Nt = N2; break;
        default: W = W3; bias = b3; C = C3; Nt = N3; break;
    }
    const int n0 = blockIdx.y * 64;
    if (n0 >= Nt) return;
    const int m0 = blockIdx.x * 64;

    __shared__ float As[16 * 68];
    __shared__ float Bs[16 * 68];
    const int t  = threadIdx.x;
    const int tm = t & 15;
    const int tn = t >> 4;

    float acc[4][4];
    #pragma unroll
    for (int r = 0; r < 4; ++r)
        #pragma unroll
        for (int c = 0; c < 4; ++c) acc[r][c] = 0.f;

    for (int k0 = 0; k0 < CS_; k0 += 16) {
        {
            int m = t >> 2, kb = (t & 3) * 4;
            float4 a4 = *(const float4*)(A + (size_t)(m0 + m) * CS_ + k0 + kb);
            As[(kb + 0) * 68 + m] = a4.x;
            As[(kb + 1) * 68 + m] = a4.y;
            As[(kb + 2) * 68 + m] = a4.z;
            As[(kb + 3) * 68 + m] = a4.w;
        }
        {
            int kk = t >> 4, n = (t & 15) * 4;
            int gn = n0 + n;
            const float* wr = W + (size_t)(k0 + kk) * Nt;
            float4 b4;
            b4.x = (gn + 0 < Nt) ? wr[gn + 0] : 0.f;
            b4.y = (gn + 1 < Nt) ? wr[gn + 1] : 0.f;
            b4.z = (gn + 2 < Nt) ? wr[gn + 2] : 0.f;
            b4.w = (gn + 3 < Nt) ? wr[gn + 3] : 0.f;
            *(float4*)(Bs + kk * 68 + n) = b4;
        }
        __syncthreads();
        #pragma unroll
        for (int kk = 0; kk < 16; ++kk) {
            float4 a4 = *(const float4*)(As + kk * 68 + tm * 4);
            float4 b4 = *(const float4*)(Bs + kk * 68 + tn * 4);
            float am[4] = {a4.x, a4.y, a4.z, a4.w};
            float bn[4] = {b4.x, b4.y, b4.z, b4.w};
            #pragma unroll
            for (int r = 0; r < 4; ++r)
                #pragma unroll
                for (int c = 0; c < 4; ++c)
                    acc[r][c] = fmaf(am[r], bn[c], acc[r][c]);
        }
        __syncthreads();
    }
    #pragma unroll
    for (int r = 0; r < 4; ++r) {
        int gm = m0 + tm * 4 + r;
        int gn = n0 + tn * 4;
        float* cr = C + (size_t)gm * Nt;
        #pragma unroll
        for (int c = 0; c < 4; ++c)
            if (gn + c < Nt) cr[gn + c] = acc[r][c] + bias[gn + c];
    }
}

// ---------------------------------------------------------------------------
// Points + layouts for the qkpt GEMM and the AV step.
//   qp/kp[n][48pt][3]; vcat[n][512] (v 0..191 | v_pts 192..479)
//   qcat[h][n][28] = [q | qp];  kcat[h][n][28] = [k*SC_QK | kp*hw]
//   qn[h][n] = 0.5*hw*|qp|^2;   kn[h][n] = 0.5*hw*|kp|^2
// ---------------------------------------------------------------------------
__global__ __launch_bounds__(192) void prep_points(
    const float* __restrict__ lqp, const float* __restrict__ lkvp,
    const float* __restrict__ rot, const float* __restrict__ trans,
    const float* __restrict__ kvb, const float* __restrict__ q,
    const float* __restrict__ hwraw,
    float* __restrict__ qp, float* __restrict__ kp,
    float* __restrict__ vcat, float* __restrict__ qcat,
    float* __restrict__ kcat, float* __restrict__ qn, float* __restrict__ kn)
{
    const int n = blockIdx.x;
    const int t = threadIdx.x;
    const float* R = rot   + n * 9;
    const float* T = trans + n * 3;

    // Phase A: global-frame points
    if (t < 48) {
        float p0 = lqp[n * 144 + t];
        float p1 = lqp[n * 144 + 48 + t];
        float p2 = lqp[n * 144 + 96 + t];
        float* d = qp + n * 144 + t * 3;
        d[0] = R[0]*p0 + R[1]*p1 + R[2]*p2 + T[0];
        d[1] = R[3]*p0 + R[4]*p1 + R[5]*p2 + T[1];
        d[2] = R[6]*p0 + R[7]*p1 + R[8]*p2 + T[2];
    } else {
        int jj = t - 48;    // 0..143
        float p0 = lkvp[n * 432 + jj];
        float p1 = lkvp[n * 432 + 144 + jj];
        float p2 = lkvp[n * 432 + 288 + jj];
        float g0 = R[0]*p0 + R[1]*p1 + R[2]*p2 + T[0];
        float g1 = R[3]*p0 + R[4]*p1 + R[5]*p2 + T[1];
        float g2 = R[6]*p0 + R[7]*p1 + R[8]*p2 + T[2];
        int h = jj / 12, idx = jj % 12;
        if (idx < 4) {
            float* d = kp + n * 144 + (h * 4 + idx) * 3;
            d[0] = g0; d[1] = g1; d[2] = g2;
        } else {
            float* d = vcat + (size_t)n * 512 + 192 + h * 24 + (idx - 4) * 3;
            d[0] = g0; d[1] = g1; d[2] = g2;
        }
    }
    // v part of vcat
    vcat[(size_t)n * 512 + t] = kvb[(size_t)n * 384 + (t >> 4) * 32 + 16 + (t & 15)];
    __syncthreads();

    // Phase B: GEMM operand layouts
    {
        int h = t >> 4, c = t & 15;
        qcat[((size_t)h * 512 + n) * 28 + c] = q[(size_t)n * 192 + t];
        kcat[((size_t)h * 512 + n) * 28 + c] = kvb[(size_t)n * 384 + h * 32 + c] * SC_QK;
    }
    if (t < 144) {
        int h = t / 12;
        float hw = softplus_(hwraw[h]) * SC_HW;
        qcat[((size_t)h * 512 + n) * 28 + 16 + (t - h * 12)] = qp[n * 144 + t];
        kcat[((size_t)h * 512 + n) * 28 + 16 + (t - h * 12)] = kp[n * 144 + t] * hw;
    }
    if (t < 24) {
        int h = t % 12;
        float hw = softplus_(hwraw[h]) * SC_HW;
        const float* src = (t < 12) ? (qp + n * 144 + h * 12) : (kp + n * 144 + h * 12);
        float s = 0.f;
        #pragma unroll
        for (int r = 0; r < 12; ++r) { float v = src[r]; s = fmaf(v, v, s); }
        float* dst = (t < 12) ? qn : kn;
        dst[h * 512 + n] = 0.5f * hw * s;
    }
}

// ---------------------------------------------------------------------------
// Pre-logits GEMM: att[h,i,j] = sc_qk q.k - 0.5 hw |qp-kp|^2 + mask term.
// 64x64 tile per block, K=28; grid (jt 8, it 8, h 12).
// ---------------------------------------------------------------------------
__global__ __launch_bounds__(256) void qkpt_gemm(
    const float* __restrict__ qcat, const float* __restrict__ kcat,
    const float* __restrict__ qn,   const float* __restrict__ kn,
    const float* __restrict__ mask, float* __restrict__ att)
{
    const int jt = blockIdx.x, it = blockIdx.y, h = blockIdx.z;
    __shared__ float As[28 * 68];
    __shared__ float Bs[28 * 68];
    __shared__ float qn_s[64], kn_s[64], mI[64], mJ[64];

    const int t  = threadIdx.x;
    const int tm = t & 15;
    const int tn = t >> 4;

    const float* Aq = qcat + ((size_t)h * 512 + it * 64) * 28;
    const float* Bk = kcat + ((size_t)h * 512 + jt * 64) * 28;
    for (int idx = t; idx < 448; idx += 256) {
        int row = idx / 7, c4 = idx % 7;
        float4 a4 = *(const float4*)(Aq + row * 28 + c4 * 4);
        As[(c4 * 4 + 0) * 68 + row] = a4.x;
        As[(c4 * 4 + 1) * 68 + row] = a4.y;
        As[(c4 * 4 + 2) * 68 + row] = a4.z;
        As[(c4 * 4 + 3) * 68 + row] = a4.w;
        float4 b4 = *(const float4*)(Bk + row * 28 + c4 * 4);
        Bs[(c4 * 4 + 0) * 68 + row] = b4.x;
        Bs[(c4 * 4 + 1) * 68 + row] = b4.y;
        Bs[(c4 * 4 + 2) * 68 + row] = b4.z;
        Bs[(c4 * 4 + 3) * 68 + row] = b4.w;
    }
    if (t < 64) {
        qn_s[t] = qn[h * 512 + it * 64 + t];
        mI[t]   = mask[it * 64 + t];
    } else if (t < 128) {
        kn_s[t - 64] = kn[h * 512 + jt * 64 + (t - 64)];
        mJ[t - 64]   = mask[jt * 64 + (t - 64)];
    }
    __syncthreads();

    float acc[4][4];
    #pragma unroll
    for (int r = 0; r < 4; ++r)
        #pragma unroll
        for (int c = 0; c < 4; ++c) acc[r][c] = 0.f;

    #pragma unroll
    for (int kk = 0; kk < 28; ++kk) {
        float4 a4 = *(const float4*)(As + kk * 68 + tm * 4);
        float4 b4 = *(const float4*)(Bs + kk * 68 + tn * 4);
        float am[4] = {a4.x, a4.y, a4.z, a4.w};
        float bn[4] = {b4.x, b4.y, b4.z, b4.w};
        #pragma unroll
        for (int r = 0; r < 4; ++r)
            #pragma unroll
            for (int c = 0; c < 4; ++c)
                acc[r][c] = fmaf(am[r], bn[c], acc[r][c]);
    }

    #pragma unroll
    for (int r = 0; r < 4; ++r) {
        const int i_ = it * 64 + tm * 4 + r;
        float* dst = att + ((size_t)h * 512 + i_) * 512 + jt * 64 + tn * 4;
        float4 o;
        float qnr = qn_s[tm * 4 + r], mir = mI[tm * 4 + r];
        o.x = acc[r][0] - qnr - kn_s[tn*4+0] + INF_ * (mir * mJ[tn*4+0] - 1.f);
        o.y = acc[r][1] - qnr - kn_s[tn*4+1] + INF_ * (mir * mJ[tn*4+1] - 1.f);
        o.z = acc[r][2] - qnr - kn_s[tn*4+2] + INF_ * (mir * mJ[tn*4+2] - 1.f);
        o.w = acc[r][3] - qnr - kn_s[tn*4+3] + INF_ * (mir * mJ[tn*4+3] - 1.f);
        *(float4*)dst = o;
    }
}

// ---------------------------------------------------------------------------
// z pass 1: att[h,i,j] += sc_b * (z[i,j,:] . W_b + b_b).  Grid (jt 8, i 512).
// 64-row z tile staged in LDS; wave = 3 heads; W_b via scalar loads.
// ---------------------------------------------------------------------------
__global__ __launch_bounds__(256) void logits_k(
    const float* __restrict__ z, const float* __restrict__ Wb,
    const float* __restrict__ bb, float* __restrict__ att)
{
    __shared__ float ztile[64 * 132];
    const int jt   = blockIdx.x;
    const int i    = blockIdx.y;
    const int jb   = jt * 64;
    const int t    = threadIdx.x;
    const int lane = t & 63;

    const int h0 = __builtin_amdgcn_readfirstlane((t >> 6) * 3);
    const float bbA = bb[h0], bbB = bb[h0 + 1], bbC = bb[h0 + 2];

    const float4* zsrc = (const float4*)z + ((size_t)i * N_ + jb) * 32;
    #pragma unroll
    for (int k2 = 0; k2 < 8; ++k2) {
        int idx = t + k2 * 256;
        int rr = idx >> 5, c4 = idx & 31;
        *(float4*)(ztile + rr * 132 + c4 * 4) = zsrc[(size_t)rr * 32 + c4];
    }
    __syncthreads();

    float b0 = bbA, b1 = bbB, b2 = bbC;
    const float4* zrow = (const float4*)(ztile + lane * 132);
    #pragma unroll 8
    for (int c4 = 0; c4 < 32; ++c4) {
        float4 z4 = zrow[c4];
        float zc[4] = {z4.x, z4.y, z4.z, z4.w};
        #pragma unroll
        for (int cc = 0; cc < 4; ++cc) {
            const int c = c4 * 4 + cc;
            b0 = fmaf(zc[cc], Wb[c * 12 + h0    ], b0);
            b1 = fmaf(zc[cc], Wb[c * 12 + h0 + 1], b1);
            b2 = fmaf(zc[cc], Wb[c * 12 + h0 + 2], b2);
        }
    }

    const size_t base = ((size_t)h0 * 512 + i) * 512 + jb + lane;
    att[base]              = fmaf(SC_B, b0, att[base]);
    att[base + 262144]     = fmaf(SC_B, b1, att[base + 262144]);
    att[base + 2 * 262144] = fmaf(SC_B, b2, att[base + 2 * 262144]);
}

// ---------------------------------------------------------------------------
// Softmax + o + o_pt + point finish.  Grid 512, 384 threads (6 waves).
// ---------------------------------------------------------------------------
__global__ __launch_bounds__(384) void smax_av(
    float* __restrict__ att, const float* __restrict__ vcat,
    const float* __restrict__ rot, const float* __restrict__ trans,
    float* __restrict__ cat)
{
    __shared__ float a_s[12 * 516];
    __shared__ float opt_s[288];
    const int i    = blockIdx.x;
    const int t    = threadIdx.x;
    const int lane = t & 63;

    // load logits
    for (int idx = t; idx < 1536; idx += 384) {
        int h = idx >> 7, j4 = idx & 127;
        *(float4*)(a_s + h * 516 + j4 * 4) =
            *((const float4*)att + ((size_t)h * 512 + i) * 128 + j4);
    }
    __syncthreads();

    // softmax: 6 waves x 2 heads
    {
        const int w = t >> 6;
        #pragma unroll
        for (int hh = 0; hh < 2; ++hh) {
            const int h = w * 2 + hh;
            float* row = a_s + h * 516;
            float4 v0 = *(float4*)(row + lane * 8);
            float4 v1 = *(float4*)(row + lane * 8 + 4);
            float m = fmaxf(fmaxf(fmaxf(v0.x, v0.y), fmaxf(v0.z, v0.w)),
                            fmaxf(fmaxf(v1.x, v1.y), fmaxf(v1.z, v1.w)));
            #pragma unroll
            for (int off = 32; off > 0; off >>= 1)
                m = fmaxf(m, __shfl_xor(m, off));
            v0.x = __expf(v0.x - m); v0.y = __expf(v0.y - m);
            v0.z = __expf(v0.z - m); v0.w = __expf(v0.w - m);
            v1.x = __expf(v1.x - m); v1.y = __expf(v1.y - m);
            v1.z = __expf(v1.z - m); v1.w = __expf(v1.w - m);
            float s = v0.x + v0.y + v0.z + v0.w + v1.x + v1.y + v1.z + v1.w;
            #pragma unroll
            for (int off = 32; off > 0; off >>= 1)
                s += __shfl_xor(s, off);
            float inv = 1.f / s;
            v0.x *= inv; v0.y *= inv; v0.z *= inv; v0.w *= inv;
            v1.x *= inv; v1.y *= inv; v1.z *= inv; v1.w *= inv;
            *(float4*)(row + lane * 8)     = v0;
            *(float4*)(row + lane * 8 + 4) = v1;
        }
    }
    __syncthreads();

    // write probs back (for opair_k)
    for (int idx = t; idx < 1536; idx += 384) {
        int h = idx >> 7, j4 = idx & 127;
        *((float4*)att + ((size_t)h * 512 + i) * 128 + j4) =
            *(const float4*)(a_s + h * 516 + j4 * 4);
    }

    // o / o_pt
    if (t < 240) {
        const int o0 = 2 * t;
        const int h  = (o0 < 192) ? (o0 >> 4) : ((o0 - 192) / 24);
        const float2* vrow = (const float2*)vcat + t;
        float accx = 0.f, accy = 0.f;
        #pragma unroll 8
        for (int j = 0; j < 512; ++j) {
            float2 v2 = vrow[(size_t)j * 256];
            float aj  = a_s[h * 516 + j];
            accx = fmaf(aj, v2.x, accx);
            accy = fmaf(aj, v2.y, accy);
        }
        if (o0 < 192) {
            cat[(size_t)i * 2112 + o0]     = accx;
            cat[(size_t)i * 2112 + o0 + 1] = accy;
        } else {
            opt_s[o0 - 192] = accx;
            opt_s[o0 - 191] = accy;
        }
    }
    __syncthreads();

    if (t < 96) {
        const float* R = rot   + i * 9;
        const float* T = trans + i * 3;
        float g0 = opt_s[t * 3 + 0] - T[0];
        float g1 = opt_s[t * 3 + 1] - T[1];
        float g2 = opt_s[t * 3 + 2] - T[2];
        float x  = R[0]*g0 + R[3]*g1 + R[6]*g2;
        float y  = R[1]*g0 + R[4]*g1 + R[7]*g2;
        float zz = R[2]*g0 + R[5]*g1 + R[8]*g2;
        float nrm = sqrtf(x*x + y*y + zz*zz + EPS_);
        float* cr = cat + (size_t)i * 2112;
        cr[192 + t] = x;
        cr[288 + t] = y;
        cr[384 + t] = zz;
        cr[480 + t] = nrm;
    }
}

// ---------------------------------------------------------------------------
// o_pair = a . z  (z pass 2, L3-fed).  Grid 512, 512 threads (8 waves).
// thread = (c4 in 0..31, jg in 0..15); probs read from global (L1 broadcast).
// ---------------------------------------------------------------------------
__global__ __launch_bounds__(512) void opair_k(
    const float* __restrict__ att, const float* __restrict__ z,
    float* __restrict__ cat)
{
    __shared__ float pb[16 * 6 * 132];
    const int i  = blockIdx.x;
    const int t  = threadIdx.x;
    const int c4 = t & 31;
    const int jg = t >> 5;          // 0..15, 32 j each

    float4 acc[12];
    #pragma unroll
    for (int h = 0; h < 12; ++h) acc[h] = make_float4(0.f, 0.f, 0.f, 0.f);

    const float4* zr = (const float4*)z + (size_t)i * (N_ * 32) + c4;
    #pragma unroll 2
    for (int j4b = 0; j4b < 8; ++j4b) {
        const int jb = jg * 32 + j4b * 4;
        float4 zv[4];
        #pragma unroll
        for (int u = 0; u < 4; ++u) zv[u] = zr[(size_t)(jb + u) * 32];
        #pragma unroll
        for (int h = 0; h < 12; ++h) {
            float4 a4 = *(const float4*)(att + ((size_t)h * 512 + i) * 512 + jb);
            acc[h].x = fmaf(a4.x, zv[0].x, acc[h].x);
            acc[h].y = fmaf(a4.x, zv[0].y, acc[h].y);
            acc[h].z = fmaf(a4.x, zv[0].z, acc[h].z);
            acc[h].w = fmaf(a4.x, zv[0].w, acc[h].w);
            acc[h].x = fmaf(a4.y, zv[1].x, acc[h].x);
            acc[h].y = fmaf(a4.y, zv[1].y, acc[h].y);
            acc[h].z = fmaf(a4.y, zv[1].z, acc[h].z);
            acc[h].w = fmaf(a4.y, zv[1].w, acc[h].w);
            acc[h].x = fmaf(a4.z, zv[2].x, acc[h].x);
            acc[h].y = fmaf(a4.z, zv[2].y, acc[h].y);
            acc[h].z = fmaf(a4.z, zv[2].z, acc[h].z);
            acc[h].w = fmaf(a4.z, zv[2].w, acc[h].w);
            acc[h].x = fmaf(a4.w, zv[3].x, acc[h].x);
            acc[h].y = fmaf(a4.w, zv[3].y, acc[h].y);
            acc[h].z = fmaf(a4.w, zv[3].z, acc[h].z);
            acc[h].w = fmaf(a4.w, zv[3].w, acc[h].w);
        }
    }

    #pragma unroll
    for (int half = 0; half < 2; ++half) {
        __syncthreads();
        #pragma unroll
        for (int hh = 0; hh < 6; ++hh)
            *(float4*)(pb + (size_t)(jg * 6 + hh) * 132 + c4 * 4) = acc[half * 6 + hh];
        __syncthreads();
        #pragma unroll
        for (int k = 0; k < 2; ++k) {
            const int idx = t + k * 512;          // 0..1023
            if (idx < 768) {
                const int hh = idx >> 7, c = idx & 127;
                float s = 0.f;
                #pragma unroll
                for (int g = 0; g < 16; ++g)
                    s += pb[(size_t)(g * 6 + hh) * 132 + c];
                cat[(size_t)i * 2112 + 576 + half * 768 + idx] = s;
            }
        }
    }
}

// ---------------------------------------------------------------------------
// Output GEMM: K=2112 split 11 ways into gpart[kc][512][384], then reduce.
// ---------------------------------------------------------------------------
__global__ __launch_bounds__(256) void gemm_ksplit(
    const float* __restrict__ A, const float* __restrict__ W,
    float* __restrict__ P)
{
    const int kc = blockIdx.z;
    const int m0 = blockIdx.x * 64;
    const int n0 = blockIdx.y * 64;

    __shared__ float As[16 * 68];
    __shared__ float Bs[16 * 68];
    const int t  = threadIdx.x;
    const int tm = t & 15;
    const int tn = t >> 4;

    float acc[4][4];
    #pragma unroll
    for (int r = 0; r < 4; ++r)
        #pragma unroll
        for (int c = 0; c < 4; ++c) acc[r][c] = 0.f;

    const int kbeg = kc * 192;
    for (int k0 = kbeg; k0 < kbeg + 192; k0 += 16) {
        {
            int m = t >> 2, kb = (t & 3) * 4;
            float4 a4 = *(const float4*)(A + (size_t)(m0 + m) * 2112 + k0 + kb);
            As[(kb + 0) * 68 + m] = a4.x;
            As[(kb + 1) * 68 + m] = a4.y;
            As[(kb + 2) * 68 + m] = a4.z;
            As[(kb + 3) * 68 + m] = a4.w;
        }
        {
            int kk = t >> 4, n = (t & 15) * 4;
            float4 b4 = *(const float4*)(W + (size_t)(k0 + kk) * 384 + n0 + n);
            *(float4*)(Bs + kk * 68 + n) = b4;
        }
        __syncthreads();
        #pragma unroll
        for (int kk = 0; kk < 16; ++kk) {
            float4 a4 = *(const float4*)(As + kk * 68 + tm * 4);
            float4 b4 = *(const float4*)(Bs + kk * 68 + tn * 4);
            float am[4] = {a4.x, a4.y, a4.z, a4.w};
            float bn[4] = {b4.x, b4.y, b4.z, b4.w};
            #pragma unroll
            for (int r = 0; r < 4; ++r)
                #pragma unroll
                for (int c = 0; c < 4; ++c)
                    acc[r][c] = fmaf(am[r], bn[c], acc[r][c]);
        }
        __syncthreads();
    }
    float* Pk = P + (size_t)kc * (512 * 384);
    #pragma unroll
    for (int r = 0; r < 4; ++r) {
        int gm = m0 + tm * 4 + r;
        *(float4*)(Pk + (size_t)gm * 384 + n0 + tn * 4) =
            make_float4(acc[r][0], acc[r][1], acc[r][2], acc[r][3]);
    }
}

__global__ __launch_bounds__(256) void reduce_out(
    const float* __restrict__ P, const float* __restrict__ bias,
    float* __restrict__ out)
{
    int idx = blockIdx.x * 256 + threadIdx.x;   // float4 index, 49152 total
    const float4* b4 = (const float4*)bias;
    float4 s = b4[idx % 96];
    const float4* P4 = (const float4*)P;
    #pragma unroll
    for (int g = 0; g < 11; ++g) {
        float4 v = P4[(size_t)g * 49152 + idx];
        s.x += v.x; s.y += v.y; s.z += v.z; s.w += v.w;
    }
    ((float4*)out)[idx] = s;
}

// ---------------------------------------------------------------------------
extern "C" void kernel_launch(void* const* d_in, const int* in_sizes, int n_in,
                              void* d_out, int out_size, void* d_ws, size_t ws_size,
                              hipStream_t stream)
{
    const float* s     = (const float*)d_in[0];
    const float* z     = (const float*)d_in[1];
    const float* rot   = (const float*)d_in[2];
    const float* trans = (const float*)d_in[3];
    const float* mask  = (const float*)d_in[4];
    const float* W_q   = (const float*)d_in[5];
    const float* b_q   = (const float*)d_in[6];
    const float* W_kv  = (const float*)d_in[7];
    const float* b_kv  = (const float*)d_in[8];
    const float* W_qp  = (const float*)d_in[9];
    const float* b_qp  = (const float*)d_in[10];
    const float* W_kvp = (const float*)d_in[11];
    const float* b_kvp = (const float*)d_in[12];
    const float* W_b   = (const float*)d_in[13];
    const float* b_b   = (const float*)d_in[14];
    const float* hw    = (const float*)d_in[15];
    const float* W_out = (const float*)d_in[16];
    const float* b_out = (const float*)d_in[17];
    float* out = (float*)d_out;
    float* ws  = (float*)d_ws;

    // workspace (floats), ~29.5 MB total. att holds pre-logits -> logits ->
    // probs in place.
    float* att   = ws;                       // 3145728
    float* cat   = att   + 3145728;          // 1081344
    float* q     = cat   + 1081344;          // 98304
    float* kvb   = q     + 98304;            // 196608
    float* lqp   = kvb   + 196608;           // 73728
    float* lkvp  = lqp   + 73728;            // 221184
    float* qp    = lkvp  + 221184;           // 73728
    float* kp    = qp    + 73728;            // 73728
    float* vcat  = kp    + 73728;            // 262144
    float* qcat  = vcat  + 262144;           // 172032
    float* kcat  = qcat  + 172032;           // 172032
    float* qn    = kcat  + 172032;           // 6144
    float* kn    = qn    + 6144;             // 6144
    float* gpart = kn    + 6144;             // 2162688

    proj_gemm<<<dim3(8, 7, 4), 256, 0, stream>>>(
        s,
        W_q,   b_q,   q,    192,
        W_kv,  b_kv,  kvb,  384,
        W_qp,  b_qp,  lqp,  144,
        W_kvp, b_kvp, lkvp, 432);
    prep_points<<<512, 192, 0, stream>>>(lqp, lkvp, rot, trans, kvb, q, hw,
                                         qp, kp, vcat, qcat, kcat, qn, kn);
    qkpt_gemm<<<dim3(8, 8, 12), 256, 0, stream>>>(qcat, kcat, qn, kn, mask, att);
    logits_k<<<dim3(8, 512), 256, 0, stream>>>(z, W_b, b_b, att);
    smax_av<<<512, 384, 0, stream>>>(att, vcat, rot, trans, cat);
    opair_k<<<512, 512, 0, stream>>>(att, z, cat);
    gemm_ksplit<<<dim3(8, 6, 11), 256, 0, stream>>>(cat, W_out, gpart);
    reduce_out<<<192, 256, 0, stream>>>(gpart, b_out, out);
}